// Round 1
// baseline (322.342 us; speedup 1.0000x reference)
//
#include <hip/hip_runtime.h>
#include <hip/hip_bf16.h>

#define IN_F   4096
#define OUT_F  11008
#define TOKENS 2048

typedef __attribute__((ext_vector_type(8))) short bf16x8;
typedef __attribute__((ext_vector_type(4))) short bf16x4;
typedef __attribute__((ext_vector_type(4))) float f32x4;

#define BM 128
#define BN 128
#define BK 32
#define LDK 40   // padded LDS row length (bf16 elems); 80B stride -> <=2-way bank alias

static __device__ __forceinline__ short f2bf(float f) {
    return __builtin_bit_cast(short, __float2bfloat16(f));
}

__global__ __launch_bounds__(256, 2) void qgemm_kernel(
    const float* __restrict__ x,              // [2048][4096] f32
    const int*   __restrict__ qweight,        // [512][11008] packed 4b along K
    const int*   __restrict__ qzeros,         // [32][1376]   packed 4b along N
    const int*   __restrict__ qscales,        // [32][11008]  uint8 values
    const float* __restrict__ qscales_zeros,  // [11008]
    const float* __restrict__ qscales_scales, // [11008]
    float* __restrict__ out)                  // [2048][11008] f32
{
    __shared__ __align__(16) unsigned short A_lds[BM][LDK];
    __shared__ __align__(16) unsigned short B_lds[BN][LDK];

    const int tid  = threadIdx.x;
    const int lane = tid & 63;
    const int wid  = tid >> 6;       // 0..3
    const int wrow = wid >> 1;       // 0..1 (64-row half)
    const int wcol = wid & 1;        // 0..1 (64-col half)

    // XCD-aware bijective swizzle: grid = 16*86 = 1376, 1376 % 8 == 0
    const int nwg = gridDim.x;
    const int cpx = nwg >> 3;
    const int bid = blockIdx.x;
    const int wg  = (bid & 7) * cpx + (bid >> 3);
    const int mtiles = TOKENS / BM;  // 16
    const int mt = wg % mtiles;
    const int nt = wg / mtiles;
    const int m0 = mt * BM;
    const int n0 = nt * BN;

    // ---- B-staging ownership: fixed 2 columns per thread for the whole K loop
    const int qrow = tid >> 6;            // 0..3  (qweight row within tile)
    const int nc   = (tid & 63) << 1;     // 0..126 (even column within tile)
    const int ncol = n0 + nc;

    const float qz0 = qscales_zeros[ncol];
    const float qz1 = qscales_zeros[ncol + 1];
    const float ss0 = qscales_scales[ncol];
    const float ss1 = qscales_scales[ncol + 1];

    float s0 = 0.f, b0 = 0.f, s1 = 0.f, b1 = 0.f;

    const int lr = lane & 15;             // fragment row/col selector
    const int lk = (lane >> 4) << 3;      // 0,8,16,24 : k-offset within fragment

    f32x4 acc[4][4];
    #pragma unroll
    for (int i = 0; i < 4; ++i)
        #pragma unroll
        for (int j = 0; j < 4; ++j) {
            f32x4 z = {0.f, 0.f, 0.f, 0.f};
            acc[i][j] = z;
        }

    for (int kt = 0; kt < IN_F / BK; ++kt) {
        const int k0 = kt * BK;

        // group = k/128 changes every 4 K-steps; refresh scale/zero then
        if ((kt & 3) == 0) {
            const int g = kt >> 2;
            const int2 sc = *reinterpret_cast<const int2*>(&qscales[g * OUT_F + ncol]);
            const int  zw = qzeros[g * (OUT_F / 8) + (ncol >> 3)];
            const int  sh = (nc & 7) << 2;
            const int  z0 = ((zw >> sh) & 0xF) + 1;
            const int  z1 = ((zw >> (sh + 4)) & 0xF) + 1;
            s0 = ((float)sc.x - qz0) * ss0;
            s1 = ((float)sc.y - qz1) * ss1;
            b0 = -(float)z0 * s0;
            b1 = -(float)z1 * s1;
        }

        __syncthreads();   // previous tile fully consumed

        // ---- stage A: 128x32 f32 -> bf16 (coalesced float4, 4 passes)
        #pragma unroll
        for (int p = 0; p < 4; ++p) {
            const int idx = tid + (p << 8);
            const int am  = idx >> 3;            // 0..127
            const int ac  = (idx & 7) << 2;      // 0,4,...,28
            const float4 v = *reinterpret_cast<const float4*>(
                &x[(m0 + am) * IN_F + k0 + ac]);
            bf16x4 av;
            av[0] = f2bf(v.x);
            av[1] = f2bf(v.y);
            av[2] = f2bf(v.z);
            av[3] = f2bf(v.w);
            *reinterpret_cast<bf16x4*>(&A_lds[am][ac]) = av;
        }

        // ---- stage B: 32x128 dequant; one int2 -> 2 columns x 8 k-values
        {
            const int2 w2 = *reinterpret_cast<const int2*>(
                &qweight[(k0 / 8 + qrow) * OUT_F + ncol]);
            bf16x8 wv0, wv1;
            #pragma unroll
            for (int j = 0; j < 8; ++j) {
                wv0[j] = f2bf((float)((w2.x >> (4 * j)) & 0xF) * s0 + b0);
                wv1[j] = f2bf((float)((w2.y >> (4 * j)) & 0xF) * s1 + b1);
            }
            *reinterpret_cast<bf16x8*>(&B_lds[nc][qrow << 3])     = wv0;
            *reinterpret_cast<bf16x8*>(&B_lds[nc + 1][qrow << 3]) = wv1;
        }

        __syncthreads();   // tile staged

        // ---- fragments (single ds_read_b128 each) + 16 MFMA
        bf16x8 af[4], bfr[4];
        #pragma unroll
        for (int f = 0; f < 4; ++f)
            af[f] = *reinterpret_cast<const bf16x8*>(
                &A_lds[(wrow << 6) + (f << 4) + lr][lk]);
        #pragma unroll
        for (int f = 0; f < 4; ++f)
            bfr[f] = *reinterpret_cast<const bf16x8*>(
                &B_lds[(wcol << 6) + (f << 4) + lr][lk]);

        #pragma unroll
        for (int i = 0; i < 4; ++i)
            #pragma unroll
            for (int j = 0; j < 4; ++j)
                acc[i][j] = __builtin_amdgcn_mfma_f32_16x16x32_bf16(
                    af[i], bfr[j], acc[i][j], 0, 0, 0);
    }

    // ---- epilogue: C/D layout col=lane&15, row=(lane>>4)*4+reg (m89/m91)
    const int orow = m0 + (wrow << 6) + ((lane >> 4) << 2);
    const int ocol = n0 + (wcol << 6) + lr;
    #pragma unroll
    for (int i = 0; i < 4; ++i)
        #pragma unroll
        for (int j = 0; j < 4; ++j) {
            const int r0 = orow + (i << 4);
            const int c  = ocol + (j << 4);
            #pragma unroll
            for (int r = 0; r < 4; ++r)
                out[(r0 + r) * OUT_F + c] = acc[i][j][r];
        }
}

extern "C" void kernel_launch(void* const* d_in, const int* in_sizes, int n_in,
                              void* d_out, int out_size, void* d_ws, size_t ws_size,
                              hipStream_t stream) {
    const float* xp       = (const float*)d_in[0];
    const int*   qweight  = (const int*)d_in[1];
    const int*   qzeros   = (const int*)d_in[2];
    const int*   qscales  = (const int*)d_in[3];
    const float* qsz      = (const float*)d_in[4];
    const float* qss      = (const float*)d_in[5];
    // d_in[6] = g_idx: identity grouping (k/128), folded into the kernel.
    float* outp = (float*)d_out;

    const int grid = (TOKENS / BM) * (OUT_F / BN);   // 16 * 86 = 1376
    qgemm_kernel<<<grid, 256, 0, stream>>>(xp, qweight, qzeros, qscales, qsz, qss, outp);
}

// Round 2
// 274.042 us; speedup vs baseline: 1.1762x; 1.1762x over previous
//
#include <hip/hip_runtime.h>
#include <hip/hip_fp16.h>
#include <stdint.h>

#define IN_F   4096
#define OUT_F  11008
#define TOKENS 2048
#define BM 128
#define BN 128
#define BK 32
#define NT (IN_F / BK)    // 128 K-steps
#define NGROUP 32

typedef _Float16 f16;
typedef __attribute__((ext_vector_type(2))) _Float16 f16x2;
typedef __attribute__((ext_vector_type(8))) _Float16 f16x8;
typedef __attribute__((ext_vector_type(4))) float f32x4;

typedef __attribute__((address_space(3))) uint32_t lds_u32_t;
typedef const __attribute__((address_space(1))) uint32_t glb_u32_t;

static __device__ __forceinline__ void gload_lds16(const void* g, void* l) {
    __builtin_amdgcn_global_load_lds((glb_u32_t*)g, (lds_u32_t*)l, 16, 0, 0);
}

// dequant one packed word -> 8 f16 in pair-permuted k-order (j, j+4)
static __device__ __forceinline__ f16x8 dequant8(uint32_t w, f16x2 sv, f16x2 zv) {
    uint32_t p0 = (w & 0x000F000Fu) | 0x64006400u;           // 1024 + nibble (exact f16)
    uint32_t p1 = ((w >> 4)  & 0x000F000Fu) | 0x64006400u;
    uint32_t p2 = ((w >> 8)  & 0x000F000Fu) | 0x64006400u;
    uint32_t p3 = ((w >> 12) & 0x000F000Fu) | 0x64006400u;
    f16x2 h0 = (__builtin_bit_cast(f16x2, p0) + zv) * sv;    // exact (w - z - 1), then * s
    f16x2 h1 = (__builtin_bit_cast(f16x2, p1) + zv) * sv;
    f16x2 h2 = (__builtin_bit_cast(f16x2, p2) + zv) * sv;
    f16x2 h3 = (__builtin_bit_cast(f16x2, p3) + zv) * sv;
    f16x8 o;
    o[0] = h0[0]; o[1] = h0[1];
    o[2] = h1[0]; o[3] = h1[1];
    o[4] = h2[0]; o[5] = h2[1];
    o[6] = h3[0]; o[7] = h3[1];
    return o;
}

// pre-pass: x f32 -> f16 with intra-octet permutation (0,4,1,5,2,6,3,7)
__global__ __launch_bounds__(256) void cvt_perm_kernel(const float* __restrict__ x,
                                                       f16* __restrict__ xws) {
    const int o = blockIdx.x * 256 + threadIdx.x;   // octet id
    const float4 a = *reinterpret_cast<const float4*>(x + (size_t)o * 8);
    const float4 b = *reinterpret_cast<const float4*>(x + (size_t)o * 8 + 4);
    f16x8 v;
    v[0] = (f16)a.x; v[1] = (f16)b.x; v[2] = (f16)a.y; v[3] = (f16)b.y;
    v[4] = (f16)a.z; v[5] = (f16)b.z; v[6] = (f16)a.w; v[7] = (f16)b.w;
    *reinterpret_cast<f16x8*>(xws + (size_t)o * 8) = v;
}

template<bool USE_WS>
__global__ __launch_bounds__(256, 2) void qgemm_kernel(
    const float*    __restrict__ x,
    const f16*      __restrict__ xws,
    const uint32_t* __restrict__ qweight,
    const uint32_t* __restrict__ qzeros,
    const int*      __restrict__ qscales,
    const float*    __restrict__ qscales_zeros,
    const float*    __restrict__ qscales_scales,
    float*          __restrict__ out)
{
    // [128][32] f16, unpadded; 16B chunk at (row, slot), slot = chunk ^ ((row>>1)&3)
    __shared__ __align__(16) f16 A_lds[BM * BK];
    __shared__ __align__(16) f16 B_lds[BN * BK];

    const int tid  = threadIdx.x;
    const int lane = tid & 63;
    const int wid  = tid >> 6;
    const int wrow = wid >> 1;
    const int wcol = wid & 1;

    // XCD-aware bijective swizzle (grid = 1376, %8 == 0)
    const int nwg = gridDim.x;
    const int cpx = nwg >> 3;
    const int bid = blockIdx.x;
    const int wg  = (bid & 7) * cpx + (bid >> 3);
    const int mt  = wg % (TOKENS / BM);
    const int nt  = wg / (TOKENS / BM);
    const int m0  = mt * BM;
    const int n0  = nt * BN;

    // ---------- B side: thread owns 1 column, 2 k-octets ----------
    const int nb   = tid & 127;
    const int qsel = tid >> 7;            // octets 2qsel, 2qsel+1
    const int ncol = n0 + nb;
    const float ssv   = qscales_scales[ncol];
    const float qzssv = qscales_zeros[ncol] * ssv;

    const int bs0 = nb * BK + ((2 * qsel)     ^ ((nb >> 1) & 3)) * 8;
    const int bs1 = nb * BK + ((2 * qsel + 1) ^ ((nb >> 1) & 3)) * 8;
    const uint32_t* bsrc = qweight + (size_t)(2 * qsel) * OUT_F + ncol;

    uint32_t wA = bsrc[0];                // prefetched packed words (k-step 0)
    uint32_t wB = bsrc[OUT_F];
    int      sw = qscales[ncol];          // prefetched group-0 scale word
    uint32_t zw = qzeros[ncol >> 3];      // prefetched group-0 zeros word
    f16x2 sv, zv;

    // ---------- A side ----------
    // ws path: 2 global_load_lds per thread (per-wave instr), linear dest, swizzled source
    const int c0   = wid * 128 + lane;    // chunk id of instr 0
    const int c1   = c0 + 64;
    const int row0 = c0 >> 2, row1 = c1 >> 2;
    const int q0   = (c0 & 3) ^ ((row0 >> 1) & 3);
    const int q1   = (c1 & 3) ^ ((row1 >> 1) & 3);
    const f16* asrc0 = xws + (size_t)(m0 + row0) * IN_F + q0 * 8;
    const f16* asrc1 = xws + (size_t)(m0 + row1) * IN_F + q1 * 8;
    f16* adst0 = A_lds + (wid * 2)     * 512;
    f16* adst1 = A_lds + (wid * 2 + 1) * 512;
    // fallback path: in-kernel cvt, permuted + swizzled store
    const int frow = tid >> 2;
    const int faq  = tid & 3;

    // ---------- fragment read offsets (loop-invariant) ----------
    const int lr = lane & 15;
    const int lo = lane >> 4;             // k-octet
    int offA[4], offB[4];
    #pragma unroll
    for (int f = 0; f < 4; ++f) {
        const int ra = wrow * 64 + f * 16 + lr;
        offA[f] = ra * BK + (lo ^ ((ra >> 1) & 3)) * 8;
        const int rb = wcol * 64 + f * 16 + lr;
        offB[f] = rb * BK + (lo ^ ((rb >> 1) & 3)) * 8;
    }

    f32x4 acc[4][4];
    #pragma unroll
    for (int i = 0; i < 4; ++i)
        #pragma unroll
        for (int j = 0; j < 4; ++j) {
            f32x4 z = {0.f, 0.f, 0.f, 0.f};
            acc[i][j] = z;
        }

    for (int kt = 0; kt < NT; ++kt) {
        if ((kt & 3) == 0) {
            // build group constants from prefetched words; prefetch next group
            const float sf = (float)sw * ssv - qzssv;
            const int   z  = (int)((zw >> ((ncol & 7) * 4)) & 0xFu);
            const f16 sh = (f16)sf;
            const f16 zh = (f16)(float)(-(1025 + z));   // -(1024 + (z+1)), exact in f16
            sv[0] = sh; sv[1] = sh;
            zv[0] = zh; zv[1] = zh;
            const int g1 = (kt >> 2) + 1;
            if (g1 < NGROUP) {
                sw = qscales[(size_t)g1 * OUT_F + ncol];
                zw = qzeros[(size_t)g1 * (OUT_F / 8) + (ncol >> 3)];
            }
        }

        __syncthreads();   // previous tile consumed

        // ---- stage B: dequant prefetched words -> swizzled LDS (conflict-free b128)
        *reinterpret_cast<f16x8*>(B_lds + bs0) = dequant8(wA, sv, zv);
        *reinterpret_cast<f16x8*>(B_lds + bs1) = dequant8(wB, sv, zv);

        // ---- stage A
        if (USE_WS) {
            gload_lds16(asrc0 + kt * BK, adst0);
            gload_lds16(asrc1 + kt * BK, adst1);
        } else {
            #pragma unroll
            for (int i = 0; i < 2; ++i) {
                const int row = frow + 64 * i;
                const float* xp = x + (size_t)(m0 + row) * IN_F + kt * BK + faq * 8;
                const float4 v0 = *reinterpret_cast<const float4*>(xp);
                const float4 v1 = *reinterpret_cast<const float4*>(xp + 4);
                f16x8 v;
                v[0] = (f16)v0.x; v[1] = (f16)v1.x; v[2] = (f16)v0.y; v[3] = (f16)v1.y;
                v[4] = (f16)v0.z; v[5] = (f16)v1.z; v[6] = (f16)v0.w; v[7] = (f16)v1.w;
                *reinterpret_cast<f16x8*>(A_lds + row * BK + (faq ^ ((row >> 1) & 3)) * 8) = v;
            }
        }

        __syncthreads();   // tile staged (vmcnt drained by compiler)

        // prefetch next step's packed B words under the MFMA phase
        if (kt + 1 < NT) {
            const uint32_t* p = bsrc + (size_t)(kt + 1) * (4 * OUT_F);
            wA = p[0];
            wB = p[OUT_F];
        }

        f16x8 af[4], bfr[4];
        #pragma unroll
        for (int f = 0; f < 4; ++f)
            af[f] = *reinterpret_cast<const f16x8*>(A_lds + offA[f]);
        #pragma unroll
        for (int f = 0; f < 4; ++f)
            bfr[f] = *reinterpret_cast<const f16x8*>(B_lds + offB[f]);

        #pragma unroll
        for (int i = 0; i < 4; ++i)
            #pragma unroll
            for (int j = 0; j < 4; ++j)
                acc[i][j] = __builtin_amdgcn_mfma_f32_16x16x32_f16(
                    af[i], bfr[j], acc[i][j], 0, 0, 0);
    }

    // ---- epilogue: C/D layout col=lane&15, row=(lane>>4)*4+reg
    const int orow = m0 + (wrow << 6) + ((lane >> 4) << 2);
    const int ocol = n0 + (wcol << 6) + lr;
    #pragma unroll
    for (int i = 0; i < 4; ++i)
        #pragma unroll
        for (int j = 0; j < 4; ++j) {
            const int r0 = orow + (i << 4);
            const int c  = ocol + (j << 4);
            #pragma unroll
            for (int r = 0; r < 4; ++r)
                out[(size_t)(r0 + r) * OUT_F + c] = acc[i][j][r];
        }
}

extern "C" void kernel_launch(void* const* d_in, const int* in_sizes, int n_in,
                              void* d_out, int out_size, void* d_ws, size_t ws_size,
                              hipStream_t stream) {
    const float*    xp  = (const float*)d_in[0];
    const uint32_t* qw  = (const uint32_t*)d_in[1];
    const uint32_t* qz  = (const uint32_t*)d_in[2];
    const int*      qs  = (const int*)d_in[3];
    const float*    qsz = (const float*)d_in[4];
    const float*    qss = (const float*)d_in[5];
    // d_in[6] = g_idx: identity grouping (k/128), folded into the kernel.
    float* outp = (float*)d_out;

    const int grid = (TOKENS / BM) * (OUT_F / BN);   // 1376
    const size_t need = (size_t)TOKENS * IN_F * sizeof(f16);   // 16 MiB

    if (ws_size >= need) {
        f16* xws = (f16*)d_ws;
        cvt_perm_kernel<<<(TOKENS * IN_F / 8) / 256, 256, 0, stream>>>(xp, xws);
        qgemm_kernel<true><<<grid, 256, 0, stream>>>(xp, xws, qw, qz, qs, qsz, qss, outp);
    } else {
        qgemm_kernel<false><<<grid, 256, 0, stream>>>(xp, (const f16*)nullptr,
                                                      qw, qz, qs, qsz, qss, outp);
    }
}

// Round 3
// 257.348 us; speedup vs baseline: 1.2526x; 1.0649x over previous
//
#include <hip/hip_runtime.h>
#include <hip/hip_fp16.h>
#include <stdint.h>

#define IN_F   4096
#define OUT_F  11008
#define TOKENS 2048
#define BM 256
#define BN 128
#define BK 64
#define NT (IN_F / BK)     // 64 K-tiles
#define NGROUP 32
#define OPW (OUT_F / 8)    // 1376 packed-zero words per group row

typedef _Float16 f16;
typedef __attribute__((ext_vector_type(2))) _Float16 f16x2;
typedef __attribute__((ext_vector_type(8))) _Float16 f16x8;
typedef __attribute__((ext_vector_type(4))) float f32x4;

typedef __attribute__((address_space(3))) uint32_t lds_u32_t;
typedef const __attribute__((address_space(1))) uint32_t glb_u32_t;

static __device__ __forceinline__ void gload_lds16(const void* g, void* l) {
    __builtin_amdgcn_global_load_lds((glb_u32_t*)g, (lds_u32_t*)l, 16, 0, 0);
}

// dequant one packed word -> 8 f16 in pair-permuted k-order (j, j+4)
static __device__ __forceinline__ f16x8 dequant8(uint32_t w, f16x2 sv, f16x2 zv) {
    uint32_t p0 = (w & 0x000F000Fu) | 0x64006400u;           // 1024 + nibble (exact f16)
    uint32_t p1 = ((w >> 4)  & 0x000F000Fu) | 0x64006400u;
    uint32_t p2 = ((w >> 8)  & 0x000F000Fu) | 0x64006400u;
    uint32_t p3 = ((w >> 12) & 0x000F000Fu) | 0x64006400u;
    f16x2 h0 = (__builtin_bit_cast(f16x2, p0) + zv) * sv;    // exact (w - z - 1), then * s
    f16x2 h1 = (__builtin_bit_cast(f16x2, p1) + zv) * sv;
    f16x2 h2 = (__builtin_bit_cast(f16x2, p2) + zv) * sv;
    f16x2 h3 = (__builtin_bit_cast(f16x2, p3) + zv) * sv;
    f16x8 o;
    o[0] = h0[0]; o[1] = h0[1];
    o[2] = h1[0]; o[3] = h1[1];
    o[4] = h2[0]; o[5] = h2[1];
    o[6] = h3[0]; o[7] = h3[1];
    return o;
}

// pre-pass: x f32 -> f16 with intra-octet pair permutation (0,4,1,5,2,6,3,7)
__global__ __launch_bounds__(256) void cvt_perm_kernel(const float* __restrict__ x,
                                                       f16* __restrict__ xws) {
    const int o = blockIdx.x * 256 + threadIdx.x;   // octet id
    const float4 a = *reinterpret_cast<const float4*>(x + (size_t)o * 8);
    const float4 b = *reinterpret_cast<const float4*>(x + (size_t)o * 8 + 4);
    f16x8 v;
    v[0] = (f16)a.x; v[1] = (f16)b.x; v[2] = (f16)a.y; v[3] = (f16)b.y;
    v[4] = (f16)a.z; v[5] = (f16)b.z; v[6] = (f16)a.w; v[7] = (f16)b.w;
    *reinterpret_cast<f16x8*>(xws + (size_t)o * 8) = v;
}

template<bool USE_WS>
__global__ __launch_bounds__(512, 1) void qgemm_kernel(
    const float*    __restrict__ x,
    const f16*      __restrict__ xws,
    const uint32_t* __restrict__ qweight,
    const uint32_t* __restrict__ qzeros,
    const int*      __restrict__ qscales,
    const float*    __restrict__ qscales_zeros,
    const float*    __restrict__ qscales_scales,
    float*          __restrict__ out)
{
    // chunk (row, slot) holds k-octet (slot ^ (row&7)) — conflict-free per 8-lane phase
    __shared__ __align__(16) f16 Abuf[2][BM * BK];   // 2 x 32 KiB
    __shared__ __align__(16) f16 Bbuf[2][BN * BK];   // 2 x 16 KiB

    const int tid  = threadIdx.x;
    const int lane = tid & 63;
    const int wid  = tid >> 6;      // 0..7
    const int wm   = wid >> 1;      // 0..3 (M quarter)
    const int wn   = wid & 1;       // 0..1 (N half)

    // XCD ownership: mt = blockIdx&7 -> each XCD keeps one 2MB A-panel in its L2
    const int mt = blockIdx.x & 7;
    const int nt = blockIdx.x >> 3;
    const int m0 = mt * BM;
    const int n0 = nt * BN;

    // ---------- B side: thread owns 1 column, octet rows o1 and o1+4 ----------
    const int colb = tid & 127;
    const int o1   = tid >> 7;           // 0..3
    const int ncol = n0 + colb;
    const float ssv   = qscales_scales[ncol];
    const float qzssv = qscales_zeros[ncol] * ssv;
    const int bo0 = colb * BK + ((o1    ) ^ (colb & 7)) * 8;
    const int bo1 = colb * BK + ((o1 + 4) ^ (colb & 7)) * 8;
    const uint32_t* bptr = qweight + (size_t)o1 * OUT_F + ncol;

    // ---------- A side: 4 chunks/thread, linear LDS dest, swizzled source ----------
    const f16*   asrc[4];
    const float* fsrc[4];
    int aoff[4];
    #pragma unroll
    for (int i = 0; i < 4; ++i) {
        const int cid = i * 512 + tid;
        const int row = cid >> 3, slot = cid & 7;
        const int oct = slot ^ (row & 7);
        asrc[i] = xws + (size_t)(m0 + row) * IN_F + oct * 8;
        fsrc[i] = x   + (size_t)(m0 + row) * IN_F + oct * 8;
        aoff[i] = cid * 8;               // f16 elems (16B chunks)
    }

    // ---------- fragment read offsets ----------
    const int lr = lane & 15;
    const int lo = lane >> 4;            // k-octet within 32-k step
    int offA[2][4], offB[2][4];
    #pragma unroll
    for (int k2 = 0; k2 < 2; ++k2)
        #pragma unroll
        for (int f = 0; f < 4; ++f) {
            const int ra = wm * 64 + f * 16 + lr;
            offA[k2][f] = ra * BK + ((k2 * 4 + lo) ^ (ra & 7)) * 8;
            const int rb = wn * 64 + f * 16 + lr;
            offB[k2][f] = rb * BK + ((k2 * 4 + lo) ^ (rb & 7)) * 8;
        }

    f32x4 acc[4][4];
    #pragma unroll
    for (int i = 0; i < 4; ++i)
        #pragma unroll
        for (int j = 0; j < 4; ++j) {
            f32x4 z = {0.f, 0.f, 0.f, 0.f};
            acc[i][j] = z;
        }

    uint32_t wa0, wb0, wa1, wb1;
    int sw; uint32_t zw;
    f16x2 sv, zv;

    auto mkconsts = [&]() {
        const float sf = (float)sw * ssv - qzssv;
        const int   z  = (int)((zw >> ((ncol & 7) * 4)) & 0xFu);
        const f16 sh = (f16)sf;
        const f16 zh = (f16)(float)(-(1025 + z));   // -(1024 + (z+1)), exact in f16
        sv[0] = sh; sv[1] = sh;
        zv[0] = zh; zv[1] = zh;
    };
    auto load_bw = [&](int t_, uint32_t& a_, uint32_t& b_) {
        const uint32_t* p = bptr + (size_t)t_ * 8 * OUT_F;
        a_ = p[0];
        b_ = p[(size_t)4 * OUT_F];
    };
    auto stage_B = [&](int buf, uint32_t a_, uint32_t b_) {
        *reinterpret_cast<f16x8*>(&Bbuf[buf][bo0]) = dequant8(a_, sv, zv);
        *reinterpret_cast<f16x8*>(&Bbuf[buf][bo1]) = dequant8(b_, sv, zv);
    };
    auto stage_A = [&](int buf, int t_) {
        if constexpr (USE_WS) {
            #pragma unroll
            for (int i = 0; i < 4; ++i)
                gload_lds16(asrc[i] + (size_t)t_ * BK, &Abuf[buf][aoff[i]]);
        } else {
            #pragma unroll
            for (int i = 0; i < 4; ++i) {
                const float* p = fsrc[i] + (size_t)t_ * BK;
                const float4 v0 = *reinterpret_cast<const float4*>(p);
                const float4 v1 = *reinterpret_cast<const float4*>(p + 4);
                f16x8 v;
                v[0] = (f16)v0.x; v[1] = (f16)v1.x; v[2] = (f16)v0.y; v[3] = (f16)v1.y;
                v[4] = (f16)v0.z; v[5] = (f16)v1.z; v[6] = (f16)v0.w; v[7] = (f16)v1.w;
                *reinterpret_cast<f16x8*>(&Abuf[buf][aoff[i]]) = v;
            }
        }
    };
    auto compute = [&](int buf) {
        #pragma unroll
        for (int k2 = 0; k2 < 2; ++k2) {
            f16x8 af[4], bf[4];
            #pragma unroll
            for (int f = 0; f < 4; ++f)
                af[f] = *reinterpret_cast<const f16x8*>(&Abuf[buf][offA[k2][f]]);
            #pragma unroll
            for (int f = 0; f < 4; ++f)
                bf[f] = *reinterpret_cast<const f16x8*>(&Bbuf[buf][offB[k2][f]]);
            __builtin_amdgcn_s_setprio(1);
            #pragma unroll
            for (int i = 0; i < 4; ++i)
                #pragma unroll
                for (int j = 0; j < 4; ++j)
                    acc[i][j] = __builtin_amdgcn_mfma_f32_16x16x32_f16(
                        af[i], bf[j], acc[i][j], 0, 0, 0);
            __builtin_amdgcn_s_setprio(0);
        }
    };

    // ---------------- prologue: stage tile 0, prime prefetches ----------------
    stage_A(0, 0);
    load_bw(0, wa0, wb0);
    sw = qscales[ncol];
    zw = qzeros[ncol >> 3];
    mkconsts();                       // group 0 (tiles 0,1)
    stage_B(0, wa0, wb0);
    load_bw(1, wa1, wb1);
    sw = qscales[OUT_F + ncol];       // group 1 prefetch
    zw = qzeros[OPW + (ncol >> 3)];
    asm volatile("s_waitcnt vmcnt(0)" ::: "memory");
    asm volatile("s_waitcnt lgkmcnt(0)" ::: "memory");
    __builtin_amdgcn_s_barrier();
    asm volatile("" ::: "memory");

    // ---------------- main loop: 2 K-tiles per body ----------------
    for (int t = 0; t < NT; t += 2) {
        // ---- half A: compute tile t (buf0), stage tile t+1 (buf1)
        stage_B(1, wa1, wb1);                       // group g = t>>1
        stage_A(1, t + 1);
        __builtin_amdgcn_sched_barrier(0);          // pin A-gloads before Bw loads
        load_bw(t + 2 < NT ? t + 2 : NT - 1, wa0, wb0);
        compute(0);
        asm volatile("s_waitcnt vmcnt(2)" ::: "memory");   // A(t+1) landed; Bw in flight
        asm volatile("s_waitcnt lgkmcnt(0)" ::: "memory");
        __builtin_amdgcn_s_barrier();
        asm volatile("" ::: "memory");

        // ---- half B: compute tile t+1 (buf1), stage tile t+2 (buf0)
        mkconsts();                                 // group g+1 (tiles t+2, t+3)
        stage_B(0, wa0, wb0);                       // garbage at t=NT-2 (never read)
        stage_A(0, t + 2 < NT ? t + 2 : NT - 1);
        __builtin_amdgcn_sched_barrier(0);
        load_bw(t + 3 < NT ? t + 3 : NT - 1, wa1, wb1);
        __builtin_amdgcn_sched_barrier(0);
        {
            const int gn = (t >> 1) + 2 < NGROUP ? (t >> 1) + 2 : NGROUP - 1;
            sw = qscales[(size_t)gn * OUT_F + ncol];
            zw = qzeros[(size_t)gn * OPW + (ncol >> 3)];
        }
        compute(1);
        asm volatile("s_waitcnt vmcnt(4)" ::: "memory");   // A(t+2) landed; Bw+sz in flight
        asm volatile("s_waitcnt lgkmcnt(0)" ::: "memory");
        __builtin_amdgcn_s_barrier();
        asm volatile("" ::: "memory");
    }

    // ---------------- epilogue: C/D layout col=lane&15, row=(lane>>4)*4+reg ----------------
    const int orow = m0 + wm * 64 + lo * 4;
    const int ocol = n0 + wn * 64 + lr;
    #pragma unroll
    for (int i = 0; i < 4; ++i)
        #pragma unroll
        for (int j = 0; j < 4; ++j) {
            #pragma unroll
            for (int r = 0; r < 4; ++r)
                out[(size_t)(orow + i * 16 + r) * OUT_F + ocol + j * 16] = acc[i][j][r];
        }
}

extern "C" void kernel_launch(void* const* d_in, const int* in_sizes, int n_in,
                              void* d_out, int out_size, void* d_ws, size_t ws_size,
                              hipStream_t stream) {
    const float*    xp  = (const float*)d_in[0];
    const uint32_t* qw  = (const uint32_t*)d_in[1];
    const uint32_t* qz  = (const uint32_t*)d_in[2];
    const int*      qs  = (const int*)d_in[3];
    const float*    qsz = (const float*)d_in[4];
    const float*    qss = (const float*)d_in[5];
    // d_in[6] = g_idx: identity grouping (k/128), folded into the kernel.
    float* outp = (float*)d_out;

    const int grid = (TOKENS / BM) * (OUT_F / BN);   // 8 * 86 = 688
    const size_t need = (size_t)TOKENS * IN_F * sizeof(f16);   // 16 MiB

    if (ws_size >= need) {
        f16* xws = (f16*)d_ws;
        cvt_perm_kernel<<<(TOKENS * IN_F / 8) / 256, 256, 0, stream>>>(xp, xws);
        qgemm_kernel<true><<<grid, 512, 0, stream>>>(xp, xws, qw, qz, qs, qsz, qss, outp);
    } else {
        qgemm_kernel<false><<<grid, 512, 0, stream>>>(xp, (const f16*)nullptr,
                                                      qw, qz, qs, qsz, qss, outp);
    }
}